// Round 18
// baseline (138.472 us; speedup 1.0000x reference)
//
#include <hip/hip_runtime.h>
#include <hip/hip_bf16.h>
#include <cstdint>

typedef unsigned short u16;
typedef __attribute__((ext_vector_type(8))) short short8;   // 8 x bf16 fragment
typedef __attribute__((ext_vector_type(4))) float f32x4;

__device__ __forceinline__ u16 f2bf(float f) {
  union { float f; uint32_t u; } c; c.f = f;
  return (u16)((c.u + 0x7FFFu + ((c.u >> 16) & 1u)) >> 16);
}

__device__ __forceinline__ uint32_t pack_bf16x2(float a, float b) {
  union { __hip_bfloat162 h; uint32_t u; } c;
  c.h = __float22bfloat162_rn(make_float2(a, b));   // v_cvt_pk_bf16_f32
  return c.u;
}

// ---------- fused prep: x->bf16 conversion + all 4 weight transposes ----------
__global__ __launch_bounds__(256) void prep_kernel(const float* __restrict__ x,
                                                   u16* __restrict__ xb,
                                                   const float* __restrict__ wq,
                                                   const float* __restrict__ wk,
                                                   const float* __restrict__ wv,
                                                   const float* __restrict__ wo,
                                                   u16* __restrict__ wqkvT,
                                                   u16* __restrict__ woT) {
  int id = blockIdx.x;
  if (id >= 2560) {   // conv part: 4096 blocks, 4 f32/thread
    int i = (id - 2560) * 256 + threadIdx.x;
    float4 v = ((const float4*)x)[i];
    ((ushort4*)xb)[i] = make_ushort4(f2bf(v.x), f2bf(v.y), f2bf(v.z), f2bf(v.w));
    return;
  }
  __shared__ float tile[64][65];
  const int K = 2048;
  int bx = id % 80, by = id / 80;
  const float* in; u16* out; int N, nx;
  if (bx < 32)      { in = wq; out = wqkvT;                          N = 2048; nx = bx; }
  else if (bx < 40) { in = wk; out = wqkvT + (size_t)2048 * 2048;    N = 512;  nx = bx - 32; }
  else if (bx < 48) { in = wv; out = wqkvT + (size_t)2560 * 2048;    N = 512;  nx = bx - 40; }
  else              { in = wo; out = woT;                            N = 2048; nx = bx - 48; }
  int n0 = nx * 64, k0 = by * 64;
  int t = threadIdx.x;
  int a = t & 63, b4 = t >> 6;
#pragma unroll
  for (int j = 0; j < 16; ++j) {
    int kk = j * 4 + b4;
    tile[kk][a] = in[(size_t)(k0 + kk) * N + n0 + a];
  }
  __syncthreads();
#pragma unroll
  for (int j = 0; j < 16; ++j) {
    int nn = j * 4 + b4;
    out[(size_t)(n0 + nn) * K + k0 + a] = f2bf(tile[a][nn]);
  }
}

// ---------- QKV GEMM with fused bias+RMSNorm+RoPE epilogue; V written transposed ----------
__global__ __launch_bounds__(256, 3) void gemm_qkv(const u16* __restrict__ A,
                                                   const u16* __restrict__ Bt,
                                                   const float* __restrict__ wq_b,
                                                   const float* __restrict__ wk_b,
                                                   const float* __restrict__ wv_b,
                                                   const float* __restrict__ qn_w,
                                                   const float* __restrict__ kn_w,
                                                   const float* __restrict__ fc,
                                                   const float* __restrict__ fs,
                                                   u16* __restrict__ Qg,
                                                   u16* __restrict__ Kg,
                                                   u16* __restrict__ Vgt) {
  const int K = 2048, nb = 24;
  __shared__ alignas(16) u16 As[2][64 * 64];
  __shared__ alignas(16) u16 Bs[2][128 * 64];
  int nwg = gridDim.x;
  int cpx = nwg >> 3;
  int bid = blockIdx.x;
  int swz = (bid & 7) * cpx + (bid >> 3);
  int m0 = (swz / nb) << 6;
  int n0 = (swz % nb) << 7;
  int tid = threadIdx.x;
  int w = tid >> 6, lane = tid & 63;
  int wr = w >> 1, wc = w & 1;
  int fr = lane & 15, hi = lane >> 4;
  int sw = fr & 7;

  auto STAGE = [&](int buf, int kt) {
#pragma unroll
    for (int i = 0; i < 2; ++i) {
      int chunk = i * 256 + tid;
      int row = chunk >> 3, c = chunk & 7;
      const u16* ga = A + (size_t)(m0 + row) * K + kt + ((c ^ (row & 7)) << 3);
      u16* la = &As[buf][(size_t)(i * 256 + w * 64) * 8];
      __builtin_amdgcn_global_load_lds((const __attribute__((address_space(1))) void*)ga,
                                       (__attribute__((address_space(3))) void*)la, 16, 0, 0);
    }
#pragma unroll
    for (int i = 0; i < 4; ++i) {
      int chunk = i * 256 + tid;
      int row = chunk >> 3, c = chunk & 7;
      const u16* gb = Bt + (size_t)(n0 + row) * K + kt + ((c ^ (row & 7)) << 3);
      u16* lb = &Bs[buf][(size_t)(i * 256 + w * 64) * 8];
      __builtin_amdgcn_global_load_lds((const __attribute__((address_space(1))) void*)gb,
                                       (__attribute__((address_space(3))) void*)lb, 16, 0, 0);
    }
  };

  f32x4 acc[2][4] = {};
  STAGE(0, 0);
  __syncthreads();
  int cur = 0;
  int c0 = (hi ^ sw) << 3, c1 = ((4 + hi) ^ sw) << 3;
  for (int kt = 0; kt < K; kt += 64) {
    if (kt + 64 < K) STAGE(cur ^ 1, kt + 64);
    short8 af[2][2], bf[4][2];
#pragma unroll
    for (int m = 0; m < 2; ++m) {
      int rb = (wr * 32 + m * 16 + fr) * 64;
      af[m][0] = *(const short8*)&As[cur][rb + c0];
      af[m][1] = *(const short8*)&As[cur][rb + c1];
    }
#pragma unroll
    for (int n = 0; n < 4; ++n) {
      int rb = (wc * 64 + n * 16 + fr) * 64;
      bf[n][0] = *(const short8*)&Bs[cur][rb + c0];
      bf[n][1] = *(const short8*)&Bs[cur][rb + c1];
    }
#pragma unroll
    for (int m = 0; m < 2; ++m)
#pragma unroll
      for (int n = 0; n < 4; ++n) {
        acc[m][n] = __builtin_amdgcn_mfma_f32_16x16x32_bf16(af[m][0], bf[n][0], acc[m][n], 0, 0, 0);
        acc[m][n] = __builtin_amdgcn_mfma_f32_16x16x32_bf16(af[m][1], bf[n][1], acc[m][n], 0, 0, 0);
      }
    __syncthreads();
    cur ^= 1;
  }

  // ---- fused epilogue ----
  int fbase = n0 + wc * 64;        // global feature col of this wave's d=0
  if (fbase >= 2560) {             // V: bias only, store TRANSPOSED Vgt[kvh*64+d][t]
    const float* bias = wv_b + (fbase - 2560);
    u16* vt = Vgt + (size_t)(fbase - 2560) * 2048;
    float bv[4];
#pragma unroll
    for (int n = 0; n < 4; ++n) bv[n] = bias[n * 16 + fr];
#pragma unroll
    for (int m = 0; m < 2; ++m)
#pragma unroll
      for (int r = 0; r < 4; ++r) {
        int t = m0 + wr * 32 + m * 16 + hi * 4 + r;
#pragma unroll
        for (int n = 0; n < 4; ++n)
          vt[(size_t)(n * 16 + fr) * 2048 + t] = f2bf(acc[m][n][r] + bv[n]);
      }
    return;
  }
  bool isQ = (fbase < 2048);
  const float* bias = isQ ? wq_b + fbase : wk_b + (fbase - 2048);
  const float* nw   = isQ ? qn_w : kn_w;
  float nscale      = isQ ? 0.18033688f : 1.0f;   // Q: fold 0.125*log2(e)
  u16* outp = isQ ? Qg + (size_t)(fbase >> 6) * 2048 * 64
                  : Kg + (size_t)((fbase - 2048) >> 6) * 2048 * 64;
  float bv[4], nwv[4];
#pragma unroll
  for (int n = 0; n < 4; ++n) {
    bv[n] = bias[n * 16 + fr];
    nwv[n] = nw[n * 16 + fr] * nscale;
  }
#pragma unroll
  for (int m = 0; m < 2; ++m) {
#pragma unroll
    for (int r = 0; r < 4; ++r) {
      int t = m0 + wr * 32 + m * 16 + hi * 4 + r;
      float v[4];
      float sq = 0.0f;
#pragma unroll
      for (int n = 0; n < 4; ++n) { v[n] = acc[m][n][r] + bv[n]; sq += v[n] * v[n]; }
      sq += __shfl_xor(sq, 1); sq += __shfl_xor(sq, 2);
      sq += __shfl_xor(sq, 4); sq += __shfl_xor(sq, 8);
      float rr = rsqrtf(sq * (1.0f / 64.0f) + 1e-5f);
#pragma unroll
      for (int n = 0; n < 4; ++n) {
        float vn = v[n] * rr * nwv[n];
        float part = __shfl_xor(vn, 1);
        int dh = n * 16 + fr;
        float c = fc[t * 32 + (dh >> 1)];
        float s = fs[t * 32 + (dh >> 1)];
        v[n] = (dh & 1) ? (part * s + vn * c) : (vn * c - part * s);
      }
#pragma unroll
      for (int n = 0; n < 4; ++n)
        outp[(size_t)t * 64 + n * 16 + fr] = f2bf(v[n]);
    }
  }
}

// ---------- bf16 GEMM: C[M][N] (f32,+bias) = A[M][K] * Bt[N][K]^T ----------
__global__ __launch_bounds__(256, 3) void gemm_bt(const u16* __restrict__ A,
                                                  const u16* __restrict__ Bt,
                                                  float* __restrict__ C,
                                                  const float* __restrict__ bias,
                                                  int M, int N, int K) {
  __shared__ alignas(16) u16 As[2][64 * 64];
  __shared__ alignas(16) u16 Bs[2][128 * 64];
  int nb = N >> 7;
  int nwg = gridDim.x;
  int cpx = nwg >> 3;
  int bid = blockIdx.x;
  int swz = (bid & 7) * cpx + (bid >> 3);
  int m0 = (swz / nb) << 6;
  int n0 = (swz % nb) << 7;
  int tid = threadIdx.x;
  int w = tid >> 6, lane = tid & 63;
  int wr = w >> 1, wc = w & 1;
  int fr = lane & 15, hi = lane >> 4;
  int sw = fr & 7;

  auto STAGE = [&](int buf, int kt) {
#pragma unroll
    for (int i = 0; i < 2; ++i) {
      int chunk = i * 256 + tid;
      int row = chunk >> 3, c = chunk & 7;
      const u16* ga = A + (size_t)(m0 + row) * K + kt + ((c ^ (row & 7)) << 3);
      u16* la = &As[buf][(size_t)(i * 256 + w * 64) * 8];
      __builtin_amdgcn_global_load_lds((const __attribute__((address_space(1))) void*)ga,
                                       (__attribute__((address_space(3))) void*)la, 16, 0, 0);
    }
#pragma unroll
    for (int i = 0; i < 4; ++i) {
      int chunk = i * 256 + tid;
      int row = chunk >> 3, c = chunk & 7;
      const u16* gb = Bt + (size_t)(n0 + row) * K + kt + ((c ^ (row & 7)) << 3);
      u16* lb = &Bs[buf][(size_t)(i * 256 + w * 64) * 8];
      __builtin_amdgcn_global_load_lds((const __attribute__((address_space(1))) void*)gb,
                                       (__attribute__((address_space(3))) void*)lb, 16, 0, 0);
    }
  };

  f32x4 acc[2][4] = {};
  STAGE(0, 0);
  __syncthreads();
  int cur = 0;
  int c0 = (hi ^ sw) << 3, c1 = ((4 + hi) ^ sw) << 3;
  for (int kt = 0; kt < K; kt += 64) {
    if (kt + 64 < K) STAGE(cur ^ 1, kt + 64);
    short8 af[2][2], bf[4][2];
#pragma unroll
    for (int m = 0; m < 2; ++m) {
      int rb = (wr * 32 + m * 16 + fr) * 64;
      af[m][0] = *(const short8*)&As[cur][rb + c0];
      af[m][1] = *(const short8*)&As[cur][rb + c1];
    }
#pragma unroll
    for (int n = 0; n < 4; ++n) {
      int rb = (wc * 64 + n * 16 + fr) * 64;
      bf[n][0] = *(const short8*)&Bs[cur][rb + c0];
      bf[n][1] = *(const short8*)&Bs[cur][rb + c1];
    }
#pragma unroll
    for (int m = 0; m < 2; ++m)
#pragma unroll
      for (int n = 0; n < 4; ++n) {
        acc[m][n] = __builtin_amdgcn_mfma_f32_16x16x32_bf16(af[m][0], bf[n][0], acc[m][n], 0, 0, 0);
        acc[m][n] = __builtin_amdgcn_mfma_f32_16x16x32_bf16(af[m][1], bf[n][1], acc[m][n], 0, 0, 0);
      }
    __syncthreads();
    cur ^= 1;
  }
#pragma unroll
  for (int m = 0; m < 2; ++m) {
#pragma unroll
    for (int n = 0; n < 4; ++n) {
      int gcol = n0 + wc * 64 + n * 16 + fr;
      float bvx = bias ? bias[gcol] : 0.0f;
#pragma unroll
      for (int r = 0; r < 4; ++r) {
        int grow = m0 + wr * 32 + m * 16 + hi * 4 + r;
        C[(size_t)grow * N + gcol] = acc[m][n][r] + bvx;
      }
    }
  }
}

// ---------- causal GQA flash attention (v10: q-tile PAIR per block, shared K/V staging) ----------
// grid 512: 16 q-pairs x 32 heads. Per block: q-tiles qa=2p, qb=2p+1 (64 rows each).
// K and V^T both stage as straight row-copies (reg dbuf, XOR-swizzled LDS writes).
__global__ __launch_bounds__(256, 2) void attn_kernel(const u16* __restrict__ Qg,
                                                      const u16* __restrict__ Kg,
                                                      const u16* __restrict__ Vgt,
                                                      const float* __restrict__ qn_w,
                                                      const float* __restrict__ kn_w,
                                                      u16* __restrict__ att) {
  __shared__ alignas(16) u16 Ks[2][64 * 64];          // [key][d], XOR-swizzled rows
  __shared__ alignas(16) u16 Vs[2][64 * 64];          // [d][key], XOR-swizzled rows
  __shared__ alignas(16) uint32_t Ps[2][4][16 * 36];  // per-tile, per-wave P

  // balanced remap: per-CU (stride-256 round-robin) pair sums uniform: (2q0+2)+(32-2q0)=34
  int bid = blockIdx.x;
  int grp = bid >> 8, idx = bid & 255;
  int q0 = idx >> 5, h = idx & 31;
  int p = (grp == 0) ? q0 : 15 - q0;
  int qa = 2 * p, qb = 2 * p + 1;
  int kvh = h >> 2;

  int tid = threadIdx.x, w = tid >> 6, lane = tid & 63;
  int fr = lane & 15, hi = lane >> 4, fk = hi * 8;

  float ba = fabsf(qn_w[lane]), bb = fabsf(kn_w[lane]);
#pragma unroll
  for (int off = 32; off >= 1; off >>= 1) {
    ba = fmaxf(ba, __shfl_xor(ba, off));
    bb = fmaxf(bb, __shfl_xor(bb, off));
  }
  float mfix = 11.5416222f * ba * bb;   // uniform softmax max (log2 domain)

  const u16* qbaseA = Qg + ((size_t)h * 2048 + qa * 64 + w * 16 + fr) * 64;
  const u16* qbaseB = Qg + ((size_t)h * 2048 + qb * 64 + w * 16 + fr) * 64;
  short8 qfa0 = *(const short8*)(qbaseA + fk);
  short8 qfa1 = *(const short8*)(qbaseA + 32 + fk);
  short8 qfb0 = *(const short8*)(qbaseB + fk);
  short8 qfb1 = *(const short8*)(qbaseB + 32 + fk);
  f32x4 oa[4] = {}, ob[4] = {};
  float lrowa = 0.0f, lrowb = 0.0f;

  // staging thread mapping: both K and V^T are straight row copies
  int row0 = tid >> 3, cc = tid & 7;
  const u16* Kbase = Kg + (size_t)kvh * 2048 * 64;
  const u16* Vtbase = Vgt + (size_t)kvh * 64 * 2048;

  short8 k0r, k1r, v0r, v1r;
  auto stage_load = [&](int kt2) {
    const u16* kb = Kbase + (size_t)kt2 * 64 * 64;
    k0r = *(const short8*)(kb + row0 * 64 + cc * 8);
    k1r = *(const short8*)(kb + (32 + row0) * 64 + cc * 8);
    const u16* vb = Vtbase + (size_t)row0 * 2048 + kt2 * 64 + cc * 8;
    v0r = *(const short8*)vb;
    v1r = *(const short8*)(vb + 32 * 2048);
  };
  auto stage_write = [&](int buf) {
    char* KsB = (char*)&Ks[buf][0];
    char* VsB = (char*)&Vs[buf][0];
    int offA = (row0 * 128 + cc * 16) ^ ((row0 & 7) << 4);
    int offB = ((32 + row0) * 128 + cc * 16) ^ ((row0 & 7) << 4);
    *(short8*)(KsB + offA) = k0r;
    *(short8*)(KsB + offB) = k1r;
    *(short8*)(VsB + offA) = v0r;
    *(short8*)(VsB + offB) = v1r;
  };

  stage_load(0);
  stage_write(0);
  __syncthreads();

  int swzr = (fr & 7) << 4;
  int qrowA = qa * 64 + w * 16 + fr;
  int qrowB = qb * 64 + w * 16 + fr;
  int nkt = qb + 1;   // kt = 0..qb

  for (int kt = 0; kt < nkt; ++kt) {
    int buf = kt & 1;
    bool lastIter = (kt == qb);
    if (!lastIter) stage_load(kt + 1);
    const char* KsB = (const char*)&Ks[buf][0];
    const char* VsB = (const char*)&Vs[buf][0];

    // ---- tile A (skip at kt == qb: fully masked) ----
    if (kt <= qa) {
      f32x4 s4[4] = {};
      __builtin_amdgcn_s_setprio(1);
#pragma unroll
      for (int g = 0; g < 4; ++g) {
        int rb = (g * 16 + fr) * 128;
        short8 b0 = *(const short8*)(KsB + ((rb + hi * 16) ^ swzr));
        short8 b1 = *(const short8*)(KsB + ((rb + 64 + hi * 16) ^ swzr));
        s4[g] = __builtin_amdgcn_mfma_f32_16x16x32_bf16(b0, qfa0, s4[g], 0, 0, 0);
        s4[g] = __builtin_amdgcn_mfma_f32_16x16x32_bf16(b1, qfa1, s4[g], 0, 0, 0);
      }
      __builtin_amdgcn_s_setprio(0);
      if (kt == qa) {
        int kbase = kt * 64 + hi * 4;
#pragma unroll
        for (int g = 0; g < 4; ++g)
#pragma unroll
          for (int r = 0; r < 4; ++r)
            if (kbase + g * 16 + r > qrowA) s4[g][r] = -1e30f;
      }
      uint32_t* Pw = &Ps[0][w][0];
#pragma unroll
      for (int g = 0; g < 4; ++g) {
        float p0 = exp2f(s4[g][0] - mfix);
        float p1 = exp2f(s4[g][1] - mfix);
        float p2 = exp2f(s4[g][2] - mfix);
        float p3 = exp2f(s4[g][3] - mfix);
        lrowa += (p0 + p1) + (p2 + p3);
        uint2 pk = make_uint2(pack_bf16x2(p0, p1), pack_bf16x2(p2, p3));
        *(uint2*)&Pw[fr * 36 + g * 8 + hi * 2] = pk;
      }
      asm volatile("s_waitcnt lgkmcnt(0)" ::: "memory");
      short8 pa0 = *(const short8*)&Pw[fr * 36 + hi * 4];
      short8 pa1 = *(const short8*)&Pw[fr * 36 + 16 + hi * 4];
      __builtin_amdgcn_s_setprio(1);
#pragma unroll
      for (int g2 = 0; g2 < 4; ++g2) {
        int rb = (g2 * 16 + fr) * 128;
        short8 vb0 = *(const short8*)(VsB + ((rb + hi * 16) ^ swzr));
        short8 vb1 = *(const short8*)(VsB + ((rb + 64 + hi * 16) ^ swzr));
        oa[g2] = __builtin_amdgcn_mfma_f32_16x16x32_bf16(pa0, vb0, oa[g2], 0, 0, 0);
        oa[g2] = __builtin_amdgcn_mfma_f32_16x16x32_bf16(pa1, vb1, oa[g2], 0, 0, 0);
      }
      __builtin_amdgcn_s_setprio(0);
    }

    // ---- tile B (diag at kt == qb) ----
    {
      f32x4 s4[4] = {};
      __builtin_amdgcn_s_setprio(1);
#pragma unroll
      for (int g = 0; g < 4; ++g) {
        int rb = (g * 16 + fr) * 128;
        short8 b0 = *(const short8*)(KsB + ((rb + hi * 16) ^ swzr));
        short8 b1 = *(const short8*)(KsB + ((rb + 64 + hi * 16) ^ swzr));
        s4[g] = __builtin_amdgcn_mfma_f32_16x16x32_bf16(b0, qfb0, s4[g], 0, 0, 0);
        s4[g] = __builtin_amdgcn_mfma_f32_16x16x32_bf16(b1, qfb1, s4[g], 0, 0, 0);
      }
      __builtin_amdgcn_s_setprio(0);
      if (lastIter) {
        int kbase = kt * 64 + hi * 4;
#pragma unroll
        for (int g = 0; g < 4; ++g)
#pragma unroll
          for (int r = 0; r < 4; ++r)
            if (kbase + g * 16 + r > qrowB) s4[g][r] = -1e30f;
      }
      uint32_t* Pw = &Ps[1][w][0];
#pragma unroll
      for (int g = 0; g < 4; ++g) {
        float p0 = exp2f(s4[g][0] - mfix);
        float p1 = exp2f(s4[g][1] - mfix);
        float p2 = exp2f(s4[g][2] - mfix);
        float p3 = exp2f(s4[g][3] - mfix);
        lrowb += (p0 + p1) + (p2 + p3);
        uint2 pk = make_uint2(pack_bf16x2(p0, p1), pack_bf16x2(p2, p3));
        *(uint2*)&Pw[fr * 36 + g * 8 + hi * 2] = pk;
      }
      asm volatile("s_waitcnt lgkmcnt(0)" ::: "memory");
      short8 pa0 = *(const short8*)&Pw[fr * 36 + hi * 4];
      short8 pa1 = *(const short8*)&Pw[fr * 36 + 16 + hi * 4];
      __builtin_amdgcn_s_setprio(1);
#pragma unroll
      for (int g2 = 0; g2 < 4; ++g2) {
        int rb = (g2 * 16 + fr) * 128;
        short8 vb0 = *(const short8*)(VsB + ((rb + hi * 16) ^ swzr));
        short8 vb1 = *(const short8*)(VsB + ((rb + 64 + hi * 16) ^ swzr));
        ob[g2] = __builtin_amdgcn_mfma_f32_16x16x32_bf16(pa0, vb0, ob[g2], 0, 0, 0);
        ob[g2] = __builtin_amdgcn_mfma_f32_16x16x32_bf16(pa1, vb1, ob[g2], 0, 0, 0);
      }
      __builtin_amdgcn_s_setprio(0);
    }

    if (!lastIter) stage_write(buf ^ 1);   // write next tile; sync publishes it
    __syncthreads();                        // ONE barrier per iteration
  }

  // epilogue: both tiles
  float rta = lrowa, rtb = lrowb;
  rta += __shfl_xor(rta, 16); rta += __shfl_xor(rta, 32);
  rtb += __shfl_xor(rtb, 16); rtb += __shfl_xor(rtb, 32);
#pragma unroll
  for (int r = 0; r < 4; ++r) {
    float lia = __shfl(rta, hi * 4 + r);
    float lib = __shfl(rtb, hi * 4 + r);
    float inva = 1.0f / lia;
    float invb = 1.0f / lib;
    size_t rowA = (size_t)(qa * 64 + w * 16 + hi * 4 + r) * 2048 + h * 64;
    size_t rowB = (size_t)(qb * 64 + w * 16 + hi * 4 + r) * 2048 + h * 64;
#pragma unroll
    for (int g2 = 0; g2 < 4; ++g2) {
      att[rowA + g2 * 16 + fr] = f2bf(oa[g2][r] * inva);
      att[rowB + g2 * 16 + fr] = f2bf(ob[g2][r] * invb);
    }
  }
}

extern "C" void kernel_launch(void* const* d_in, const int* in_sizes, int n_in,
                              void* d_out, int out_size, void* d_ws, size_t ws_size,
                              hipStream_t stream) {
  const float* x    = (const float*)d_in[0];
  const float* fc   = (const float*)d_in[1];
  const float* fs   = (const float*)d_in[2];
  // d_in[3] = mask (causal, regenerated in-kernel)
  const float* wq   = (const float*)d_in[4];
  const float* wq_b = (const float*)d_in[5];
  const float* wk   = (const float*)d_in[6];
  const float* wk_b = (const float*)d_in[7];
  const float* wv   = (const float*)d_in[8];
  const float* wv_b = (const float*)d_in[9];
  const float* wo   = (const float*)d_in[10];
  const float* wo_b = (const float*)d_in[11];
  const float* qn   = (const float*)d_in[12];
  const float* kn   = (const float*)d_in[13];
  float* out = (float*)d_out;

  char* ws = (char*)d_ws;
  u16*  xb    = (u16*)(ws);                          //  8 MB  x bf16 [2048][2048]
  u16*  wqkvT = (u16*)(ws + (size_t)(8  << 20));     // 12 MB  [3072][2048] bf16
  u16*  woT   = (u16*)(ws + (size_t)(20 << 20));     //  8 MB  [2048][2048] bf16
  u16*  Qg    = (u16*)(ws + (size_t)(52 << 20));     //  8 MB  [32][2048][64]
  u16*  Kg    = (u16*)(ws + (size_t)(60 << 20));     //  2 MB  [8][2048][64]
  u16*  Vgt   = (u16*)(ws + (size_t)(62 << 20));     //  2 MB  [8][64][2048] (V transposed)
  u16*  att   = (u16*)(ws + (size_t)(64 << 20));     //  8 MB  [2048][2048]

  prep_kernel<<<6656, 256, 0, stream>>>(x, xb, wq, wk, wv, wo, wqkvT, woT);
  gemm_qkv<<<32 * 24, 256, 0, stream>>>(xb, wqkvT, wq_b, wk_b, wv_b, qn, kn, fc, fs, Qg, Kg, Vgt);
  attn_kernel<<<512, 256, 0, stream>>>(Qg, Kg, Vgt, qn, kn, att);
  gemm_bt<<<32 * 16, 256, 0, stream>>>(att, woT, out, wo_b, 2048, 2048, 2048);
}

// Round 19
// 128.989 us; speedup vs baseline: 1.0735x; 1.0735x over previous
//
#include <hip/hip_runtime.h>
#include <hip/hip_bf16.h>
#include <cstdint>

typedef unsigned short u16;
typedef __attribute__((ext_vector_type(8))) short short8;   // 8 x bf16 fragment
typedef __attribute__((ext_vector_type(4))) float f32x4;

__device__ __forceinline__ u16 f2bf(float f) {
  union { float f; uint32_t u; } c; c.f = f;
  return (u16)((c.u + 0x7FFFu + ((c.u >> 16) & 1u)) >> 16);
}

__device__ __forceinline__ uint32_t pack_bf16x2(float a, float b) {
  union { __hip_bfloat162 h; uint32_t u; } c;
  c.h = __float22bfloat162_rn(make_float2(a, b));   // v_cvt_pk_bf16_f32
  return c.u;
}

// ---------- fused prep: x->bf16 conversion + all 4 weight transposes ----------
__global__ __launch_bounds__(256) void prep_kernel(const float* __restrict__ x,
                                                   u16* __restrict__ xb,
                                                   const float* __restrict__ wq,
                                                   const float* __restrict__ wk,
                                                   const float* __restrict__ wv,
                                                   const float* __restrict__ wo,
                                                   u16* __restrict__ wqkvT,
                                                   u16* __restrict__ woT) {
  int id = blockIdx.x;
  if (id >= 2560) {   // conv part: 4096 blocks, 4 f32/thread
    int i = (id - 2560) * 256 + threadIdx.x;
    float4 v = ((const float4*)x)[i];
    ((ushort4*)xb)[i] = make_ushort4(f2bf(v.x), f2bf(v.y), f2bf(v.z), f2bf(v.w));
    return;
  }
  __shared__ float tile[64][65];
  const int K = 2048;
  int bx = id % 80, by = id / 80;
  const float* in; u16* out; int N, nx;
  if (bx < 32)      { in = wq; out = wqkvT;                          N = 2048; nx = bx; }
  else if (bx < 40) { in = wk; out = wqkvT + (size_t)2048 * 2048;    N = 512;  nx = bx - 32; }
  else if (bx < 48) { in = wv; out = wqkvT + (size_t)2560 * 2048;    N = 512;  nx = bx - 40; }
  else              { in = wo; out = woT;                            N = 2048; nx = bx - 48; }
  int n0 = nx * 64, k0 = by * 64;
  int t = threadIdx.x;
  int a = t & 63, b4 = t >> 6;
#pragma unroll
  for (int j = 0; j < 16; ++j) {
    int kk = j * 4 + b4;
    tile[kk][a] = in[(size_t)(k0 + kk) * N + n0 + a];
  }
  __syncthreads();
#pragma unroll
  for (int j = 0; j < 16; ++j) {
    int nn = j * 4 + b4;
    out[(size_t)(n0 + nn) * K + k0 + a] = f2bf(tile[a][nn]);
  }
}

// ---------- QKV GEMM with fused bias+RMSNorm+RoPE epilogue; V written transposed ----------
__global__ __launch_bounds__(256, 3) void gemm_qkv(const u16* __restrict__ A,
                                                   const u16* __restrict__ Bt,
                                                   const float* __restrict__ wq_b,
                                                   const float* __restrict__ wk_b,
                                                   const float* __restrict__ wv_b,
                                                   const float* __restrict__ qn_w,
                                                   const float* __restrict__ kn_w,
                                                   const float* __restrict__ fc,
                                                   const float* __restrict__ fs,
                                                   u16* __restrict__ Qg,
                                                   u16* __restrict__ Kg,
                                                   u16* __restrict__ Vgt) {
  const int K = 2048, nb = 24;
  __shared__ alignas(16) u16 As[2][64 * 64];
  __shared__ alignas(16) u16 Bs[2][128 * 64];
  int nwg = gridDim.x;
  int cpx = nwg >> 3;
  int bid = blockIdx.x;
  int swz = (bid & 7) * cpx + (bid >> 3);
  int m0 = (swz / nb) << 6;
  int n0 = (swz % nb) << 7;
  int tid = threadIdx.x;
  int w = tid >> 6, lane = tid & 63;
  int wr = w >> 1, wc = w & 1;
  int fr = lane & 15, hi = lane >> 4;
  int sw = fr & 7;

  auto STAGE = [&](int buf, int kt) {
#pragma unroll
    for (int i = 0; i < 2; ++i) {
      int chunk = i * 256 + tid;
      int row = chunk >> 3, c = chunk & 7;
      const u16* ga = A + (size_t)(m0 + row) * K + kt + ((c ^ (row & 7)) << 3);
      u16* la = &As[buf][(size_t)(i * 256 + w * 64) * 8];
      __builtin_amdgcn_global_load_lds((const __attribute__((address_space(1))) void*)ga,
                                       (__attribute__((address_space(3))) void*)la, 16, 0, 0);
    }
#pragma unroll
    for (int i = 0; i < 4; ++i) {
      int chunk = i * 256 + tid;
      int row = chunk >> 3, c = chunk & 7;
      const u16* gb = Bt + (size_t)(n0 + row) * K + kt + ((c ^ (row & 7)) << 3);
      u16* lb = &Bs[buf][(size_t)(i * 256 + w * 64) * 8];
      __builtin_amdgcn_global_load_lds((const __attribute__((address_space(1))) void*)gb,
                                       (__attribute__((address_space(3))) void*)lb, 16, 0, 0);
    }
  };

  f32x4 acc[2][4] = {};
  STAGE(0, 0);
  __syncthreads();
  int cur = 0;
  int c0 = (hi ^ sw) << 3, c1 = ((4 + hi) ^ sw) << 3;
  for (int kt = 0; kt < K; kt += 64) {
    if (kt + 64 < K) STAGE(cur ^ 1, kt + 64);
    short8 af[2][2], bf[4][2];
#pragma unroll
    for (int m = 0; m < 2; ++m) {
      int rb = (wr * 32 + m * 16 + fr) * 64;
      af[m][0] = *(const short8*)&As[cur][rb + c0];
      af[m][1] = *(const short8*)&As[cur][rb + c1];
    }
#pragma unroll
    for (int n = 0; n < 4; ++n) {
      int rb = (wc * 64 + n * 16 + fr) * 64;
      bf[n][0] = *(const short8*)&Bs[cur][rb + c0];
      bf[n][1] = *(const short8*)&Bs[cur][rb + c1];
    }
#pragma unroll
    for (int m = 0; m < 2; ++m)
#pragma unroll
      for (int n = 0; n < 4; ++n) {
        acc[m][n] = __builtin_amdgcn_mfma_f32_16x16x32_bf16(af[m][0], bf[n][0], acc[m][n], 0, 0, 0);
        acc[m][n] = __builtin_amdgcn_mfma_f32_16x16x32_bf16(af[m][1], bf[n][1], acc[m][n], 0, 0, 0);
      }
    __syncthreads();
    cur ^= 1;
  }

  // ---- fused epilogue ----
  int fbase = n0 + wc * 64;        // global feature col of this wave's d=0
  if (fbase >= 2560) {             // V: bias only, store TRANSPOSED Vgt[kvh*64+d][t]
    const float* bias = wv_b + (fbase - 2560);
    u16* vt = Vgt + (size_t)(fbase - 2560) * 2048;
    float bv[4];
#pragma unroll
    for (int n = 0; n < 4; ++n) bv[n] = bias[n * 16 + fr];
#pragma unroll
    for (int m = 0; m < 2; ++m)
#pragma unroll
      for (int r = 0; r < 4; ++r) {
        int t = m0 + wr * 32 + m * 16 + hi * 4 + r;
#pragma unroll
        for (int n = 0; n < 4; ++n)
          vt[(size_t)(n * 16 + fr) * 2048 + t] = f2bf(acc[m][n][r] + bv[n]);
      }
    return;
  }
  bool isQ = (fbase < 2048);
  const float* bias = isQ ? wq_b + fbase : wk_b + (fbase - 2048);
  const float* nw   = isQ ? qn_w : kn_w;
  float nscale      = isQ ? 0.18033688f : 1.0f;   // Q: fold 0.125*log2(e)
  u16* outp = isQ ? Qg + (size_t)(fbase >> 6) * 2048 * 64
                  : Kg + (size_t)((fbase - 2048) >> 6) * 2048 * 64;
  float bv[4], nwv[4];
#pragma unroll
  for (int n = 0; n < 4; ++n) {
    bv[n] = bias[n * 16 + fr];
    nwv[n] = nw[n * 16 + fr] * nscale;
  }
#pragma unroll
  for (int m = 0; m < 2; ++m) {
#pragma unroll
    for (int r = 0; r < 4; ++r) {
      int t = m0 + wr * 32 + m * 16 + hi * 4 + r;
      float v[4];
      float sq = 0.0f;
#pragma unroll
      for (int n = 0; n < 4; ++n) { v[n] = acc[m][n][r] + bv[n]; sq += v[n] * v[n]; }
      sq += __shfl_xor(sq, 1); sq += __shfl_xor(sq, 2);
      sq += __shfl_xor(sq, 4); sq += __shfl_xor(sq, 8);
      float rr = rsqrtf(sq * (1.0f / 64.0f) + 1e-5f);
#pragma unroll
      for (int n = 0; n < 4; ++n) {
        float vn = v[n] * rr * nwv[n];
        float part = __shfl_xor(vn, 1);
        int dh = n * 16 + fr;
        float c = fc[t * 32 + (dh >> 1)];
        float s = fs[t * 32 + (dh >> 1)];
        v[n] = (dh & 1) ? (part * s + vn * c) : (vn * c - part * s);
      }
#pragma unroll
      for (int n = 0; n < 4; ++n)
        outp[(size_t)t * 64 + n * 16 + fr] = f2bf(v[n]);
    }
  }
}

// ---------- bf16 GEMM: C[M][N] (f32,+bias) = A[M][K] * Bt[N][K]^T ----------
__global__ __launch_bounds__(256, 3) void gemm_bt(const u16* __restrict__ A,
                                                  const u16* __restrict__ Bt,
                                                  float* __restrict__ C,
                                                  const float* __restrict__ bias,
                                                  int M, int N, int K) {
  __shared__ alignas(16) u16 As[2][64 * 64];
  __shared__ alignas(16) u16 Bs[2][128 * 64];
  int nb = N >> 7;
  int nwg = gridDim.x;
  int cpx = nwg >> 3;
  int bid = blockIdx.x;
  int swz = (bid & 7) * cpx + (bid >> 3);
  int m0 = (swz / nb) << 6;
  int n0 = (swz % nb) << 7;
  int tid = threadIdx.x;
  int w = tid >> 6, lane = tid & 63;
  int wr = w >> 1, wc = w & 1;
  int fr = lane & 15, hi = lane >> 4;
  int sw = fr & 7;

  auto STAGE = [&](int buf, int kt) {
#pragma unroll
    for (int i = 0; i < 2; ++i) {
      int chunk = i * 256 + tid;
      int row = chunk >> 3, c = chunk & 7;
      const u16* ga = A + (size_t)(m0 + row) * K + kt + ((c ^ (row & 7)) << 3);
      u16* la = &As[buf][(size_t)(i * 256 + w * 64) * 8];
      __builtin_amdgcn_global_load_lds((const __attribute__((address_space(1))) void*)ga,
                                       (__attribute__((address_space(3))) void*)la, 16, 0, 0);
    }
#pragma unroll
    for (int i = 0; i < 4; ++i) {
      int chunk = i * 256 + tid;
      int row = chunk >> 3, c = chunk & 7;
      const u16* gb = Bt + (size_t)(n0 + row) * K + kt + ((c ^ (row & 7)) << 3);
      u16* lb = &Bs[buf][(size_t)(i * 256 + w * 64) * 8];
      __builtin_amdgcn_global_load_lds((const __attribute__((address_space(1))) void*)gb,
                                       (__attribute__((address_space(3))) void*)lb, 16, 0, 0);
    }
  };

  f32x4 acc[2][4] = {};
  STAGE(0, 0);
  __syncthreads();
  int cur = 0;
  int c0 = (hi ^ sw) << 3, c1 = ((4 + hi) ^ sw) << 3;
  for (int kt = 0; kt < K; kt += 64) {
    if (kt + 64 < K) STAGE(cur ^ 1, kt + 64);
    short8 af[2][2], bf[4][2];
#pragma unroll
    for (int m = 0; m < 2; ++m) {
      int rb = (wr * 32 + m * 16 + fr) * 64;
      af[m][0] = *(const short8*)&As[cur][rb + c0];
      af[m][1] = *(const short8*)&As[cur][rb + c1];
    }
#pragma unroll
    for (int n = 0; n < 4; ++n) {
      int rb = (wc * 64 + n * 16 + fr) * 64;
      bf[n][0] = *(const short8*)&Bs[cur][rb + c0];
      bf[n][1] = *(const short8*)&Bs[cur][rb + c1];
    }
#pragma unroll
    for (int m = 0; m < 2; ++m)
#pragma unroll
      for (int n = 0; n < 4; ++n) {
        acc[m][n] = __builtin_amdgcn_mfma_f32_16x16x32_bf16(af[m][0], bf[n][0], acc[m][n], 0, 0, 0);
        acc[m][n] = __builtin_amdgcn_mfma_f32_16x16x32_bf16(af[m][1], bf[n][1], acc[m][n], 0, 0, 0);
      }
    __syncthreads();
    cur ^= 1;
  }
#pragma unroll
  for (int m = 0; m < 2; ++m) {
#pragma unroll
    for (int n = 0; n < 4; ++n) {
      int gcol = n0 + wc * 64 + n * 16 + fr;
      float bvx = bias ? bias[gcol] : 0.0f;
#pragma unroll
      for (int r = 0; r < 4; ++r) {
        int grow = m0 + wr * 32 + m * 16 + hi * 4 + r;
        C[(size_t)grow * N + gcol] = acc[m][n][r] + bvx;
      }
    }
  }
}

// ---------- causal GQA flash attention (v11 = v8 structure + Vgt row-copy staging) ----------
// grid 1024, 64-key tiles, single-sync dbuf LDS, 3 blocks/CU.
__global__ __launch_bounds__(256, 3) void attn_kernel(const u16* __restrict__ Qg,
                                                      const u16* __restrict__ Kg,
                                                      const u16* __restrict__ Vgt,
                                                      const float* __restrict__ qn_w,
                                                      const float* __restrict__ kn_w,
                                                      u16* __restrict__ att) {
  __shared__ alignas(16) u16 Ks[2][64 * 64];         // [key][d], XOR-swizzled rows
  __shared__ alignas(16) u16 Vs[2][64 * 64];         // [d][key], XOR-swizzled rows
  __shared__ alignas(16) uint32_t Ps[4][16 * 36];    // per-wave P: [q=fr][key-pair], stride 36

  // balanced remap: each CU's round-robin set {q0,15-q0,16+q0,31-q0} sums uniform
  int bid = blockIdx.x;
  int grp = bid >> 8, idx = bid & 255;
  int q0 = idx >> 5, h = idx & 31;
  int qt = (grp == 0) ? q0 : (grp == 1) ? 15 - q0 : (grp == 2) ? 16 + q0 : 31 - q0;
  int kvh = h >> 2;

  int tid = threadIdx.x, w = tid >> 6, lane = tid & 63;
  int fr = lane & 15, hi = lane >> 4, fk = hi * 8;

  float ba = fabsf(qn_w[lane]), bb = fabsf(kn_w[lane]);
#pragma unroll
  for (int off = 32; off >= 1; off >>= 1) {
    ba = fmaxf(ba, __shfl_xor(ba, off));
    bb = fmaxf(bb, __shfl_xor(bb, off));
  }
  float mfix = 11.5416222f * ba * bb;   // uniform softmax max (log2 domain)

  const u16* qbase = Qg + ((size_t)h * 2048 + qt * 64 + w * 16 + fr) * 64;
  short8 qf0 = *(const short8*)(qbase + fk);
  short8 qf1 = *(const short8*)(qbase + 32 + fk);
  f32x4 o[4] = {};
  float lrow = 0.0f;

  // staging: both K and V^T are straight row copies (rows of 64 u16)
  int row0 = tid >> 3, cc = tid & 7;
  const u16* Kbase = Kg + (size_t)kvh * 2048 * 64;
  const u16* Vtbase = Vgt + (size_t)kvh * 64 * 2048;

  short8 k0r, k1r, v0r, v1r;
  auto stage_load = [&](int kt2) {
    const u16* kb = Kbase + (size_t)kt2 * 64 * 64;
    k0r = *(const short8*)(kb + row0 * 64 + cc * 8);
    k1r = *(const short8*)(kb + (32 + row0) * 64 + cc * 8);
    const u16* vb = Vtbase + (size_t)row0 * 2048 + kt2 * 64 + cc * 8;
    v0r = *(const short8*)vb;
    v1r = *(const short8*)(vb + 32 * 2048);
  };
  auto stage_write = [&](int buf) {
    char* KsB = (char*)&Ks[buf][0];
    char* VsB = (char*)&Vs[buf][0];
    int offA = (row0 * 128 + cc * 16) ^ ((row0 & 7) << 4);
    int offB = ((32 + row0) * 128 + cc * 16) ^ ((row0 & 7) << 4);
    *(short8*)(KsB + offA) = k0r;
    *(short8*)(KsB + offB) = k1r;
    *(short8*)(VsB + offA) = v0r;
    *(short8*)(VsB + offB) = v1r;
  };

  stage_load(0);
  stage_write(0);
  __syncthreads();

  uint32_t* Pw = &Ps[w][0];
  int swzr = (fr & 7) << 4;
  int qrow = qt * 64 + w * 16 + fr;

  for (int kt = 0; kt <= qt; ++kt) {
    int buf = kt & 1;
    bool diag = (kt == qt);
    if (!diag) stage_load(kt + 1);   // global loads in flight under this iter's compute
    const char* KsB = (const char*)&Ks[buf][0];
    const char* VsB = (const char*)&Vs[buf][0];
    f32x4 s4[4] = {};
    __builtin_amdgcn_s_setprio(1);
#pragma unroll
    for (int g = 0; g < 4; ++g) {
      int rb = (g * 16 + fr) * 128;
      short8 b0 = *(const short8*)(KsB + ((rb + hi * 16) ^ swzr));
      short8 b1 = *(const short8*)(KsB + ((rb + 64 + hi * 16) ^ swzr));
      s4[g] = __builtin_amdgcn_mfma_f32_16x16x32_bf16(b0, qf0, s4[g], 0, 0, 0);
      s4[g] = __builtin_amdgcn_mfma_f32_16x16x32_bf16(b1, qf1, s4[g], 0, 0, 0);
    }
    __builtin_amdgcn_s_setprio(0);
    if (diag) {
      int kbase = kt * 64 + hi * 4;
#pragma unroll
      for (int g = 0; g < 4; ++g)
#pragma unroll
        for (int r = 0; r < 4; ++r)
          if (kbase + g * 16 + r > qrow) s4[g][r] = -1e30f;
    }
#pragma unroll
    for (int g = 0; g < 4; ++g) {
      float p0 = exp2f(s4[g][0] - mfix);
      float p1 = exp2f(s4[g][1] - mfix);
      float p2 = exp2f(s4[g][2] - mfix);
      float p3 = exp2f(s4[g][3] - mfix);
      lrow += (p0 + p1) + (p2 + p3);
      uint2 pk = make_uint2(pack_bf16x2(p0, p1), pack_bf16x2(p2, p3));
      *(uint2*)&Pw[fr * 36 + g * 8 + hi * 2] = pk;
    }
    asm volatile("s_waitcnt lgkmcnt(0)" ::: "memory");
    short8 pa0 = *(const short8*)&Pw[fr * 36 + hi * 4];
    short8 pa1 = *(const short8*)&Pw[fr * 36 + 16 + hi * 4];
    __builtin_amdgcn_s_setprio(1);
#pragma unroll
    for (int g2 = 0; g2 < 4; ++g2) {
      int rb = (g2 * 16 + fr) * 128;
      short8 vb0 = *(const short8*)(VsB + ((rb + hi * 16) ^ swzr));
      short8 vb1 = *(const short8*)(VsB + ((rb + 64 + hi * 16) ^ swzr));
      o[g2] = __builtin_amdgcn_mfma_f32_16x16x32_bf16(pa0, vb0, o[g2], 0, 0, 0);
      o[g2] = __builtin_amdgcn_mfma_f32_16x16x32_bf16(pa1, vb1, o[g2], 0, 0, 0);
    }
    __builtin_amdgcn_s_setprio(0);
    if (!diag) stage_write(buf ^ 1);   // write next tile; sync below publishes it
    __syncthreads();                   // ONE barrier per iteration
  }
  float rtot = lrow;
  rtot += __shfl_xor(rtot, 16);
  rtot += __shfl_xor(rtot, 32);
#pragma unroll
  for (int r = 0; r < 4; ++r) {
    float li = __shfl(rtot, hi * 4 + r);
    float inv = 1.0f / li;
    size_t rowoff = (size_t)(qt * 64 + w * 16 + hi * 4 + r) * 2048 + h * 64;
#pragma unroll
    for (int g2 = 0; g2 < 4; ++g2)
      att[rowoff + g2 * 16 + fr] = f2bf(o[g2][r] * inv);
  }
}

extern "C" void kernel_launch(void* const* d_in, const int* in_sizes, int n_in,
                              void* d_out, int out_size, void* d_ws, size_t ws_size,
                              hipStream_t stream) {
  const float* x    = (const float*)d_in[0];
  const float* fc   = (const float*)d_in[1];
  const float* fs   = (const float*)d_in[2];
  // d_in[3] = mask (causal, regenerated in-kernel)
  const float* wq   = (const float*)d_in[4];
  const float* wq_b = (const float*)d_in[5];
  const float* wk   = (const float*)d_in[6];
  const float* wk_b = (const float*)d_in[7];
  const float* wv   = (const float*)d_in[8];
  const float* wv_b = (const float*)d_in[9];
  const float* wo   = (const float*)d_in[10];
  const float* wo_b = (const float*)d_in[11];
  const float* qn   = (const float*)d_in[12];
  const float* kn   = (const float*)d_in[13];
  float* out = (float*)d_out;

  char* ws = (char*)d_ws;
  u16*  xb    = (u16*)(ws);                          //  8 MB  x bf16 [2048][2048]
  u16*  wqkvT = (u16*)(ws + (size_t)(8  << 20));     // 12 MB  [3072][2048] bf16
  u16*  woT   = (u16*)(ws + (size_t)(20 << 20));     //  8 MB  [2048][2048] bf16
  u16*  Qg    = (u16*)(ws + (size_t)(52 << 20));     //  8 MB  [32][2048][64]
  u16*  Kg    = (u16*)(ws + (size_t)(60 << 20));     //  2 MB  [8][2048][64]
  u16*  Vgt   = (u16*)(ws + (size_t)(62 << 20));     //  2 MB  [8][64][2048] (V transposed)
  u16*  att   = (u16*)(ws + (size_t)(64 << 20));     //  8 MB  [2048][2048]

  prep_kernel<<<6656, 256, 0, stream>>>(x, xb, wq, wk, wv, wo, wqkvT, woT);
  gemm_qkv<<<32 * 24, 256, 0, stream>>>(xb, wqkvT, wq_b, wk_b, wv_b, qn, kn, fc, fs, Qg, Kg, Vgt);
  attn_kernel<<<1024, 256, 0, stream>>>(Qg, Kg, Vgt, qn, kn, att);
  gemm_bt<<<32 * 16, 256, 0, stream>>>(att, woT, out, wo_b, 2048, 2048, 2048);
}

// Round 20
// 121.727 us; speedup vs baseline: 1.1376x; 1.0597x over previous
//
#include <hip/hip_runtime.h>
#include <hip/hip_bf16.h>
#include <cstdint>

typedef unsigned short u16;
typedef __attribute__((ext_vector_type(8))) short short8;   // 8 x bf16 fragment
typedef __attribute__((ext_vector_type(4))) float f32x4;

__device__ __forceinline__ u16 f2bf(float f) {
  union { float f; uint32_t u; } c; c.f = f;
  return (u16)((c.u + 0x7FFFu + ((c.u >> 16) & 1u)) >> 16);
}

__device__ __forceinline__ uint32_t pack_bf16x2(float a, float b) {
  union { __hip_bfloat162 h; uint32_t u; } c;
  c.h = __float22bfloat162_rn(make_float2(a, b));   // v_cvt_pk_bf16_f32
  return c.u;
}

// ---------- fused prep: x->bf16 conversion + all 4 weight transposes ----------
__global__ __launch_bounds__(256) void prep_kernel(const float* __restrict__ x,
                                                   u16* __restrict__ xb,
                                                   const float* __restrict__ wq,
                                                   const float* __restrict__ wk,
                                                   const float* __restrict__ wv,
                                                   const float* __restrict__ wo,
                                                   u16* __restrict__ wqkvT,
                                                   u16* __restrict__ woT) {
  int id = blockIdx.x;
  if (id >= 2560) {   // conv part: 4096 blocks, 4 f32/thread
    int i = (id - 2560) * 256 + threadIdx.x;
    float4 v = ((const float4*)x)[i];
    ((ushort4*)xb)[i] = make_ushort4(f2bf(v.x), f2bf(v.y), f2bf(v.z), f2bf(v.w));
    return;
  }
  __shared__ float tile[64][65];
  const int K = 2048;
  int bx = id % 80, by = id / 80;
  const float* in; u16* out; int N, nx;
  if (bx < 32)      { in = wq; out = wqkvT;                          N = 2048; nx = bx; }
  else if (bx < 40) { in = wk; out = wqkvT + (size_t)2048 * 2048;    N = 512;  nx = bx - 32; }
  else if (bx < 48) { in = wv; out = wqkvT + (size_t)2560 * 2048;    N = 512;  nx = bx - 40; }
  else              { in = wo; out = woT;                            N = 2048; nx = bx - 48; }
  int n0 = nx * 64, k0 = by * 64;
  int t = threadIdx.x;
  int a = t & 63, b4 = t >> 6;
#pragma unroll
  for (int j = 0; j < 16; ++j) {
    int kk = j * 4 + b4;
    tile[kk][a] = in[(size_t)(k0 + kk) * N + n0 + a];
  }
  __syncthreads();
#pragma unroll
  for (int j = 0; j < 16; ++j) {
    int nn = j * 4 + b4;
    out[(size_t)(n0 + nn) * K + k0 + a] = f2bf(tile[a][nn]);
  }
}

// ---------- QKV GEMM with fused bias+RMSNorm+RoPE epilogue; V written transposed ----------
__global__ __launch_bounds__(256, 3) void gemm_qkv(const u16* __restrict__ A,
                                                   const u16* __restrict__ Bt,
                                                   const float* __restrict__ wq_b,
                                                   const float* __restrict__ wk_b,
                                                   const float* __restrict__ wv_b,
                                                   const float* __restrict__ qn_w,
                                                   const float* __restrict__ kn_w,
                                                   const float* __restrict__ fc,
                                                   const float* __restrict__ fs,
                                                   u16* __restrict__ Qg,
                                                   u16* __restrict__ Kg,
                                                   u16* __restrict__ Vgt) {
  const int K = 2048, nb = 24;
  __shared__ alignas(16) u16 As[2][64 * 64];
  __shared__ alignas(16) u16 Bs[2][128 * 64];
  int nwg = gridDim.x;
  int cpx = nwg >> 3;
  int bid = blockIdx.x;
  int swz = (bid & 7) * cpx + (bid >> 3);
  int m0 = (swz / nb) << 6;
  int n0 = (swz % nb) << 7;
  int tid = threadIdx.x;
  int w = tid >> 6, lane = tid & 63;
  int wr = w >> 1, wc = w & 1;
  int fr = lane & 15, hi = lane >> 4;
  int sw = fr & 7;

  auto STAGE = [&](int buf, int kt) {
#pragma unroll
    for (int i = 0; i < 2; ++i) {
      int chunk = i * 256 + tid;
      int row = chunk >> 3, c = chunk & 7;
      const u16* ga = A + (size_t)(m0 + row) * K + kt + ((c ^ (row & 7)) << 3);
      u16* la = &As[buf][(size_t)(i * 256 + w * 64) * 8];
      __builtin_amdgcn_global_load_lds((const __attribute__((address_space(1))) void*)ga,
                                       (__attribute__((address_space(3))) void*)la, 16, 0, 0);
    }
#pragma unroll
    for (int i = 0; i < 4; ++i) {
      int chunk = i * 256 + tid;
      int row = chunk >> 3, c = chunk & 7;
      const u16* gb = Bt + (size_t)(n0 + row) * K + kt + ((c ^ (row & 7)) << 3);
      u16* lb = &Bs[buf][(size_t)(i * 256 + w * 64) * 8];
      __builtin_amdgcn_global_load_lds((const __attribute__((address_space(1))) void*)gb,
                                       (__attribute__((address_space(3))) void*)lb, 16, 0, 0);
    }
  };

  f32x4 acc[2][4] = {};
  STAGE(0, 0);
  __syncthreads();
  int cur = 0;
  int c0 = (hi ^ sw) << 3, c1 = ((4 + hi) ^ sw) << 3;
  for (int kt = 0; kt < K; kt += 64) {
    if (kt + 64 < K) STAGE(cur ^ 1, kt + 64);
    short8 af[2][2], bf[4][2];
#pragma unroll
    for (int m = 0; m < 2; ++m) {
      int rb = (wr * 32 + m * 16 + fr) * 64;
      af[m][0] = *(const short8*)&As[cur][rb + c0];
      af[m][1] = *(const short8*)&As[cur][rb + c1];
    }
#pragma unroll
    for (int n = 0; n < 4; ++n) {
      int rb = (wc * 64 + n * 16 + fr) * 64;
      bf[n][0] = *(const short8*)&Bs[cur][rb + c0];
      bf[n][1] = *(const short8*)&Bs[cur][rb + c1];
    }
#pragma unroll
    for (int m = 0; m < 2; ++m)
#pragma unroll
      for (int n = 0; n < 4; ++n) {
        acc[m][n] = __builtin_amdgcn_mfma_f32_16x16x32_bf16(af[m][0], bf[n][0], acc[m][n], 0, 0, 0);
        acc[m][n] = __builtin_amdgcn_mfma_f32_16x16x32_bf16(af[m][1], bf[n][1], acc[m][n], 0, 0, 0);
      }
    __syncthreads();
    cur ^= 1;
  }

  // ---- fused epilogue ----
  int fbase = n0 + wc * 64;        // global feature col of this wave's d=0
  if (fbase >= 2560) {             // V: bias only, store TRANSPOSED Vgt[kvh*64+d][t]
    const float* bias = wv_b + (fbase - 2560);
    u16* vt = Vgt + (size_t)(fbase - 2560) * 2048;
    float bv[4];
#pragma unroll
    for (int n = 0; n < 4; ++n) bv[n] = bias[n * 16 + fr];
#pragma unroll
    for (int m = 0; m < 2; ++m)
#pragma unroll
      for (int r = 0; r < 4; ++r) {
        int t = m0 + wr * 32 + m * 16 + hi * 4 + r;
#pragma unroll
        for (int n = 0; n < 4; ++n)
          vt[(size_t)(n * 16 + fr) * 2048 + t] = f2bf(acc[m][n][r] + bv[n]);
      }
    return;
  }
  bool isQ = (fbase < 2048);
  const float* bias = isQ ? wq_b + fbase : wk_b + (fbase - 2048);
  const float* nw   = isQ ? qn_w : kn_w;
  float nscale      = isQ ? 0.18033688f : 1.0f;   // Q: fold 0.125*log2(e)
  u16* outp = isQ ? Qg + (size_t)(fbase >> 6) * 2048 * 64
                  : Kg + (size_t)((fbase - 2048) >> 6) * 2048 * 64;
  float bv[4], nwv[4];
#pragma unroll
  for (int n = 0; n < 4; ++n) {
    bv[n] = bias[n * 16 + fr];
    nwv[n] = nw[n * 16 + fr] * nscale;
  }
#pragma unroll
  for (int m = 0; m < 2; ++m) {
#pragma unroll
    for (int r = 0; r < 4; ++r) {
      int t = m0 + wr * 32 + m * 16 + hi * 4 + r;
      float v[4];
      float sq = 0.0f;
#pragma unroll
      for (int n = 0; n < 4; ++n) { v[n] = acc[m][n][r] + bv[n]; sq += v[n] * v[n]; }
      sq += __shfl_xor(sq, 1); sq += __shfl_xor(sq, 2);
      sq += __shfl_xor(sq, 4); sq += __shfl_xor(sq, 8);
      float rr = rsqrtf(sq * (1.0f / 64.0f) + 1e-5f);
#pragma unroll
      for (int n = 0; n < 4; ++n) {
        float vn = v[n] * rr * nwv[n];
        float part = __shfl_xor(vn, 1);
        int dh = n * 16 + fr;
        float c = fc[t * 32 + (dh >> 1)];
        float s = fs[t * 32 + (dh >> 1)];
        v[n] = (dh & 1) ? (part * s + vn * c) : (vn * c - part * s);
      }
#pragma unroll
      for (int n = 0; n < 4; ++n)
        outp[(size_t)t * 64 + n * 16 + fr] = f2bf(v[n]);
    }
  }
}

// ---------- bf16 GEMM: C[M][N] (f32,+bias) = A[M][K] * Bt[N][K]^T ----------
// 64x64 tile, BK=64, 2-phase dbuf, chunk-XOR swizzle, 4 blocks/CU.
__global__ __launch_bounds__(256, 4) void gemm_bt(const u16* __restrict__ A,
                                                  const u16* __restrict__ Bt,
                                                  float* __restrict__ C,
                                                  const float* __restrict__ bias,
                                                  int M, int N, int K) {
  __shared__ alignas(16) u16 As[2][64 * 64];
  __shared__ alignas(16) u16 Bs[2][64 * 64];
  int nb = N >> 6;
  int nwg = gridDim.x;
  int cpx = nwg >> 3;
  int bid = blockIdx.x;
  int swz = (bid & 7) * cpx + (bid >> 3);
  int m0 = (swz / nb) << 6;
  int n0 = (swz % nb) << 6;
  int tid = threadIdx.x;
  int w = tid >> 6, lane = tid & 63;
  int wr = w >> 1, wc = w & 1;
  int fr = lane & 15, hi = lane >> 4;
  int sw = fr & 7;

  auto STAGE = [&](int buf, int kt) {
#pragma unroll
    for (int i = 0; i < 2; ++i) {
      int chunk = i * 256 + tid;
      int row = chunk >> 3, c = chunk & 7;
      const u16* ga = A + (size_t)(m0 + row) * K + kt + ((c ^ (row & 7)) << 3);
      u16* la = &As[buf][(size_t)(i * 256 + w * 64) * 8];
      __builtin_amdgcn_global_load_lds((const __attribute__((address_space(1))) void*)ga,
                                       (__attribute__((address_space(3))) void*)la, 16, 0, 0);
      const u16* gb = Bt + (size_t)(n0 + row) * K + kt + ((c ^ (row & 7)) << 3);
      u16* lb = &Bs[buf][(size_t)(i * 256 + w * 64) * 8];
      __builtin_amdgcn_global_load_lds((const __attribute__((address_space(1))) void*)gb,
                                       (__attribute__((address_space(3))) void*)lb, 16, 0, 0);
    }
  };

  f32x4 acc[2][2] = {};
  STAGE(0, 0);
  __syncthreads();
  int cur = 0;
  int c0 = (hi ^ sw) << 3, c1 = ((4 + hi) ^ sw) << 3;
  for (int kt = 0; kt < K; kt += 64) {
    if (kt + 64 < K) STAGE(cur ^ 1, kt + 64);
    short8 af[2][2], bf[2][2];
#pragma unroll
    for (int m = 0; m < 2; ++m) {
      int rb = (wr * 32 + m * 16 + fr) * 64;
      af[m][0] = *(const short8*)&As[cur][rb + c0];
      af[m][1] = *(const short8*)&As[cur][rb + c1];
    }
#pragma unroll
    for (int n = 0; n < 2; ++n) {
      int rb = (wc * 32 + n * 16 + fr) * 64;
      bf[n][0] = *(const short8*)&Bs[cur][rb + c0];
      bf[n][1] = *(const short8*)&Bs[cur][rb + c1];
    }
#pragma unroll
    for (int m = 0; m < 2; ++m)
#pragma unroll
      for (int n = 0; n < 2; ++n) {
        acc[m][n] = __builtin_amdgcn_mfma_f32_16x16x32_bf16(af[m][0], bf[n][0], acc[m][n], 0, 0, 0);
        acc[m][n] = __builtin_amdgcn_mfma_f32_16x16x32_bf16(af[m][1], bf[n][1], acc[m][n], 0, 0, 0);
      }
    __syncthreads();
    cur ^= 1;
  }
#pragma unroll
  for (int m = 0; m < 2; ++m) {
#pragma unroll
    for (int n = 0; n < 2; ++n) {
      int gcol = n0 + wc * 32 + n * 16 + fr;
      float bvx = bias ? bias[gcol] : 0.0f;
#pragma unroll
      for (int r = 0; r < 4; ++r) {
        int grow = m0 + wr * 32 + m * 16 + hi * 4 + r;
        C[(size_t)grow * N + gcol] = acc[m][n][r] + bvx;
      }
    }
  }
}

// ---------- causal GQA flash attention (v12: heavy-first remap + lsum-MFMA) ----------
// grid 1024, 64-key tiles, single-sync dbuf LDS, 3 blocks/CU.
__global__ __launch_bounds__(256, 3) void attn_kernel(const u16* __restrict__ Qg,
                                                      const u16* __restrict__ Kg,
                                                      const u16* __restrict__ Vgt,
                                                      const float* __restrict__ qn_w,
                                                      const float* __restrict__ kn_w,
                                                      u16* __restrict__ att) {
  __shared__ alignas(16) u16 Ks[2][64 * 64];         // [key][d], XOR-swizzled rows
  __shared__ alignas(16) u16 Vs[2][64 * 64];         // [d][key], XOR-swizzled rows
  __shared__ alignas(16) uint32_t Ps[4][16 * 36];    // per-wave P: [q=fr][key-pair], stride 36

  // heavy-first balanced remap: grp0 qt=31-q0 (heavy), ..., grp3 qt=q0 (light tail)
  int bid = blockIdx.x;
  int grp = bid >> 8, idx = bid & 255;
  int q0 = idx >> 5, h = idx & 31;
  int qt = (grp == 0) ? 31 - q0 : (grp == 1) ? 16 + q0 : (grp == 2) ? 15 - q0 : q0;
  int kvh = h >> 2;

  int tid = threadIdx.x, w = tid >> 6, lane = tid & 63;
  int fr = lane & 15, hi = lane >> 4, fk = hi * 8;

  float ba = fabsf(qn_w[lane]), bb = fabsf(kn_w[lane]);
#pragma unroll
  for (int off = 32; off >= 1; off >>= 1) {
    ba = fmaxf(ba, __shfl_xor(ba, off));
    bb = fmaxf(bb, __shfl_xor(bb, off));
  }
  float mfix = 11.5416222f * ba * bb;   // uniform softmax max (log2 domain)

  const u16* qbase = Qg + ((size_t)h * 2048 + qt * 64 + w * 16 + fr) * 64;
  short8 qf0 = *(const short8*)(qbase + fk);
  short8 qf1 = *(const short8*)(qbase + 32 + fk);
  short8 ones;
#pragma unroll
  for (int j = 0; j < 8; ++j) ones[j] = (short)0x3F80;   // bf16 1.0
  f32x4 o[4] = {};
  f32x4 o_l = {};   // l-sums via ones-MFMA: o_l[r] = l[q-row hi*4+r]

  // staging: both K and V^T are straight row copies (rows of 64 u16)
  int row0 = tid >> 3, cc = tid & 7;
  const u16* Kbase = Kg + (size_t)kvh * 2048 * 64;
  const u16* Vtbase = Vgt + (size_t)kvh * 64 * 2048;

  short8 k0r, k1r, v0r, v1r;
  auto stage_load = [&](int kt2) {
    const u16* kb = Kbase + (size_t)kt2 * 64 * 64;
    k0r = *(const short8*)(kb + row0 * 64 + cc * 8);
    k1r = *(const short8*)(kb + (32 + row0) * 64 + cc * 8);
    const u16* vb = Vtbase + (size_t)row0 * 2048 + kt2 * 64 + cc * 8;
    v0r = *(const short8*)vb;
    v1r = *(const short8*)(vb + 32 * 2048);
  };
  auto stage_write = [&](int buf) {
    char* KsB = (char*)&Ks[buf][0];
    char* VsB = (char*)&Vs[buf][0];
    int offA = (row0 * 128 + cc * 16) ^ ((row0 & 7) << 4);
    int offB = ((32 + row0) * 128 + cc * 16) ^ ((row0 & 7) << 4);
    *(short8*)(KsB + offA) = k0r;
    *(short8*)(KsB + offB) = k1r;
    *(short8*)(VsB + offA) = v0r;
    *(short8*)(VsB + offB) = v1r;
  };

  stage_load(0);
  stage_write(0);
  __syncthreads();

  uint32_t* Pw = &Ps[w][0];
  int swzr = (fr & 7) << 4;
  int qrow = qt * 64 + w * 16 + fr;

  for (int kt = 0; kt <= qt; ++kt) {
    int buf = kt & 1;
    bool diag = (kt == qt);
    if (!diag) stage_load(kt + 1);   // global loads in flight under this iter's compute
    const char* KsB = (const char*)&Ks[buf][0];
    const char* VsB = (const char*)&Vs[buf][0];
    f32x4 s4[4] = {};
    __builtin_amdgcn_s_setprio(1);
#pragma unroll
    for (int g = 0; g < 4; ++g) {
      int rb = (g * 16 + fr) * 128;
      short8 b0 = *(const short8*)(KsB + ((rb + hi * 16) ^ swzr));
      short8 b1 = *(const short8*)(KsB + ((rb + 64 + hi * 16) ^ swzr));
      s4[g] = __builtin_amdgcn_mfma_f32_16x16x32_bf16(b0, qf0, s4[g], 0, 0, 0);
      s4[g] = __builtin_amdgcn_mfma_f32_16x16x32_bf16(b1, qf1, s4[g], 0, 0, 0);
    }
    __builtin_amdgcn_s_setprio(0);
    if (diag) {
      int kbase = kt * 64 + hi * 4;
#pragma unroll
      for (int g = 0; g < 4; ++g)
#pragma unroll
        for (int r = 0; r < 4; ++r)
          if (kbase + g * 16 + r > qrow) s4[g][r] = -1e30f;
    }
#pragma unroll
    for (int g = 0; g < 4; ++g) {
      float p0 = exp2f(s4[g][0] - mfix);
      float p1 = exp2f(s4[g][1] - mfix);
      float p2 = exp2f(s4[g][2] - mfix);
      float p3 = exp2f(s4[g][3] - mfix);
      uint2 pk = make_uint2(pack_bf16x2(p0, p1), pack_bf16x2(p2, p3));
      *(uint2*)&Pw[fr * 36 + g * 8 + hi * 2] = pk;
    }
    asm volatile("s_waitcnt lgkmcnt(0)" ::: "memory");
    short8 pa0 = *(const short8*)&Pw[fr * 36 + hi * 4];
    short8 pa1 = *(const short8*)&Pw[fr * 36 + 16 + hi * 4];
    __builtin_amdgcn_s_setprio(1);
    o_l = __builtin_amdgcn_mfma_f32_16x16x32_bf16(pa0, ones, o_l, 0, 0, 0);
    o_l = __builtin_amdgcn_mfma_f32_16x16x32_bf16(pa1, ones, o_l, 0, 0, 0);
#pragma unroll
    for (int g2 = 0; g2 < 4; ++g2) {
      int rb = (g2 * 16 + fr) * 128;
      short8 vb0 = *(const short8*)(VsB + ((rb + hi * 16) ^ swzr));
      short8 vb1 = *(const short8*)(VsB + ((rb + 64 + hi * 16) ^ swzr));
      o[g2] = __builtin_amdgcn_mfma_f32_16x16x32_bf16(pa0, vb0, o[g2], 0, 0, 0);
      o[g2] = __builtin_amdgcn_mfma_f32_16x16x32_bf16(pa1, vb1, o[g2], 0, 0, 0);
    }
    __builtin_amdgcn_s_setprio(0);
    if (!diag) stage_write(buf ^ 1);   // write next tile; sync below publishes it
    __syncthreads();                   // ONE barrier per iteration
  }
#pragma unroll
  for (int r = 0; r < 4; ++r) {
    float inv = 1.0f / o_l[r];
    size_t rowoff = (size_t)(qt * 64 + w * 16 + hi * 4 + r) * 2048 + h * 64;
#pragma unroll
    for (int g2 = 0; g2 < 4; ++g2)
      att[rowoff + g2 * 16 + fr] = f2bf(o[g2][r] * inv);
  }
}

extern "C" void kernel_launch(void* const* d_in, const int* in_sizes, int n_in,
                              void* d_out, int out_size, void* d_ws, size_t ws_size,
                              hipStream_t stream) {
  const float* x    = (const float*)d_in[0];
  const float* fc   = (const float*)d_in[1];
  const float* fs   = (const float*)d_in[2];
  // d_in[3] = mask (causal, regenerated in-kernel)
  const float* wq   = (const float*)d_in[4];
  const float* wq_b = (const float*)d_in[5];
  const float* wk   = (const float*)d_in[6];
  const float* wk_b = (const float*)d_in[7];
  const float* wv   = (const float*)d_in[8];
  const float* wv_b = (const float*)d_in[9];
  const float* wo   = (const float*)d_in[10];
  const float* wo_b = (const float*)d_in[11];
  const float* qn   = (const float*)d_in[12];
  const float* kn   = (const float*)d_in[13];
  float* out = (float*)d_out;

  char* ws = (char*)d_ws;
  u16*  xb    = (u16*)(ws);                          //  8 MB  x bf16 [2048][2048]
  u16*  wqkvT = (u16*)(ws + (size_t)(8  << 20));     // 12 MB  [3072][2048] bf16
  u16*  woT   = (u16*)(ws + (size_t)(20 << 20));     //  8 MB  [2048][2048] bf16
  u16*  Qg    = (u16*)(ws + (size_t)(52 << 20));     //  8 MB  [32][2048][64]
  u16*  Kg    = (u16*)(ws + (size_t)(60 << 20));     //  2 MB  [8][2048][64]
  u16*  Vgt   = (u16*)(ws + (size_t)(62 << 20));     //  2 MB  [8][64][2048] (V transposed)
  u16*  att   = (u16*)(ws + (size_t)(64 << 20));     //  8 MB  [2048][2048]

  prep_kernel<<<6656, 256, 0, stream>>>(x, xb, wq, wk, wv, wo, wqkvT, woT);
  gemm_qkv<<<32 * 24, 256, 0, stream>>>(xb, wqkvT, wq_b, wk_b, wv_b, qn, kn, fc, fs, Qg, Kg, Vgt);
  attn_kernel<<<1024, 256, 0, stream>>>(Qg, Kg, Vgt, qn, kn, att);
  gemm_bt<<<32 * 32, 256, 0, stream>>>(att, woT, out, wo_b, 2048, 2048, 2048);
}

// Round 21
// 119.290 us; speedup vs baseline: 1.1608x; 1.0204x over previous
//
#include <hip/hip_runtime.h>
#include <hip/hip_bf16.h>
#include <cstdint>

typedef unsigned short u16;
typedef __attribute__((ext_vector_type(8))) short short8;   // 8 x bf16 fragment
typedef __attribute__((ext_vector_type(4))) float f32x4;

__device__ __forceinline__ u16 f2bf(float f) {
  union { float f; uint32_t u; } c; c.f = f;
  return (u16)((c.u + 0x7FFFu + ((c.u >> 16) & 1u)) >> 16);
}

__device__ __forceinline__ uint32_t pack_bf16x2(float a, float b) {
  union { __hip_bfloat162 h; uint32_t u; } c;
  c.h = __float22bfloat162_rn(make_float2(a, b));   // v_cvt_pk_bf16_f32
  return c.u;
}

// ---------- fused prep: x->bf16 conversion + all 4 weight transposes ----------
__global__ __launch_bounds__(256) void prep_kernel(const float* __restrict__ x,
                                                   u16* __restrict__ xb,
                                                   const float* __restrict__ wq,
                                                   const float* __restrict__ wk,
                                                   const float* __restrict__ wv,
                                                   const float* __restrict__ wo,
                                                   u16* __restrict__ wqkvT,
                                                   u16* __restrict__ woT) {
  int id = blockIdx.x;
  if (id >= 2560) {   // conv part: 4096 blocks, 4 f32/thread
    int i = (id - 2560) * 256 + threadIdx.x;
    float4 v = ((const float4*)x)[i];
    ((ushort4*)xb)[i] = make_ushort4(f2bf(v.x), f2bf(v.y), f2bf(v.z), f2bf(v.w));
    return;
  }
  __shared__ float tile[64][65];
  const int K = 2048;
  int bx = id % 80, by = id / 80;
  const float* in; u16* out; int N, nx;
  if (bx < 32)      { in = wq; out = wqkvT;                          N = 2048; nx = bx; }
  else if (bx < 40) { in = wk; out = wqkvT + (size_t)2048 * 2048;    N = 512;  nx = bx - 32; }
  else if (bx < 48) { in = wv; out = wqkvT + (size_t)2560 * 2048;    N = 512;  nx = bx - 40; }
  else              { in = wo; out = woT;                            N = 2048; nx = bx - 48; }
  int n0 = nx * 64, k0 = by * 64;
  int t = threadIdx.x;
  int a = t & 63, b4 = t >> 6;
#pragma unroll
  for (int j = 0; j < 16; ++j) {
    int kk = j * 4 + b4;
    tile[kk][a] = in[(size_t)(k0 + kk) * N + n0 + a];
  }
  __syncthreads();
#pragma unroll
  for (int j = 0; j < 16; ++j) {
    int nn = j * 4 + b4;
    out[(size_t)(n0 + nn) * K + k0 + a] = f2bf(tile[a][nn]);
  }
}

// ---------- QKV GEMM with fused bias+RMSNorm+RoPE epilogue; V written transposed ----------
// n-major block order within XCD: B-panel (512 KB) L2-resident, A streamed (L3-shared).
__global__ __launch_bounds__(256, 3) void gemm_qkv(const u16* __restrict__ A,
                                                   const u16* __restrict__ Bt,
                                                   const float* __restrict__ wq_b,
                                                   const float* __restrict__ wk_b,
                                                   const float* __restrict__ wv_b,
                                                   const float* __restrict__ qn_w,
                                                   const float* __restrict__ kn_w,
                                                   const float* __restrict__ fc,
                                                   const float* __restrict__ fs,
                                                   u16* __restrict__ Qg,
                                                   u16* __restrict__ Kg,
                                                   u16* __restrict__ Vgt) {
  const int K = 2048;
  __shared__ alignas(16) u16 As[2][64 * 64];
  __shared__ alignas(16) u16 Bs[2][128 * 64];
  int nwg = gridDim.x;
  int cpx = nwg >> 3;
  int bid = blockIdx.x;
  int swz = (bid & 7) * cpx + (bid >> 3);
  int m0 = (swz & 31) << 6;        // n-major: consecutive swz share the B n-panel
  int n0 = (swz >> 5) << 7;
  int tid = threadIdx.x;
  int w = tid >> 6, lane = tid & 63;
  int wr = w >> 1, wc = w & 1;
  int fr = lane & 15, hi = lane >> 4;
  int sw = fr & 7;

  auto STAGE = [&](int buf, int kt) {
#pragma unroll
    for (int i = 0; i < 2; ++i) {
      int chunk = i * 256 + tid;
      int row = chunk >> 3, c = chunk & 7;
      const u16* ga = A + (size_t)(m0 + row) * K + kt + ((c ^ (row & 7)) << 3);
      u16* la = &As[buf][(size_t)(i * 256 + w * 64) * 8];
      __builtin_amdgcn_global_load_lds((const __attribute__((address_space(1))) void*)ga,
                                       (__attribute__((address_space(3))) void*)la, 16, 0, 0);
    }
#pragma unroll
    for (int i = 0; i < 4; ++i) {
      int chunk = i * 256 + tid;
      int row = chunk >> 3, c = chunk & 7;
      const u16* gb = Bt + (size_t)(n0 + row) * K + kt + ((c ^ (row & 7)) << 3);
      u16* lb = &Bs[buf][(size_t)(i * 256 + w * 64) * 8];
      __builtin_amdgcn_global_load_lds((const __attribute__((address_space(1))) void*)gb,
                                       (__attribute__((address_space(3))) void*)lb, 16, 0, 0);
    }
  };

  f32x4 acc[2][4] = {};
  STAGE(0, 0);
  __syncthreads();
  int cur = 0;
  int c0 = (hi ^ sw) << 3, c1 = ((4 + hi) ^ sw) << 3;
  for (int kt = 0; kt < K; kt += 64) {
    if (kt + 64 < K) STAGE(cur ^ 1, kt + 64);
    short8 af[2][2], bf[4][2];
#pragma unroll
    for (int m = 0; m < 2; ++m) {
      int rb = (wr * 32 + m * 16 + fr) * 64;
      af[m][0] = *(const short8*)&As[cur][rb + c0];
      af[m][1] = *(const short8*)&As[cur][rb + c1];
    }
#pragma unroll
    for (int n = 0; n < 4; ++n) {
      int rb = (wc * 64 + n * 16 + fr) * 64;
      bf[n][0] = *(const short8*)&Bs[cur][rb + c0];
      bf[n][1] = *(const short8*)&Bs[cur][rb + c1];
    }
#pragma unroll
    for (int m = 0; m < 2; ++m)
#pragma unroll
      for (int n = 0; n < 4; ++n) {
        acc[m][n] = __builtin_amdgcn_mfma_f32_16x16x32_bf16(af[m][0], bf[n][0], acc[m][n], 0, 0, 0);
        acc[m][n] = __builtin_amdgcn_mfma_f32_16x16x32_bf16(af[m][1], bf[n][1], acc[m][n], 0, 0, 0);
      }
    __syncthreads();
    cur ^= 1;
  }

  // ---- fused epilogue ----
  int fbase = n0 + wc * 64;        // global feature col of this wave's d=0
  if (fbase >= 2560) {             // V: bias only, store TRANSPOSED Vgt[kvh*64+d][t]
    const float* bias = wv_b + (fbase - 2560);
    u16* vt = Vgt + (size_t)(fbase - 2560) * 2048;
    float bv[4];
#pragma unroll
    for (int n = 0; n < 4; ++n) bv[n] = bias[n * 16 + fr];
#pragma unroll
    for (int m = 0; m < 2; ++m)
#pragma unroll
      for (int r = 0; r < 4; ++r) {
        int t = m0 + wr * 32 + m * 16 + hi * 4 + r;
#pragma unroll
        for (int n = 0; n < 4; ++n)
          vt[(size_t)(n * 16 + fr) * 2048 + t] = f2bf(acc[m][n][r] + bv[n]);
      }
    return;
  }
  bool isQ = (fbase < 2048);
  const float* bias = isQ ? wq_b + fbase : wk_b + (fbase - 2048);
  const float* nw   = isQ ? qn_w : kn_w;
  float nscale      = isQ ? 0.18033688f : 1.0f;   // Q: fold 0.125*log2(e)
  u16* outp = isQ ? Qg + (size_t)(fbase >> 6) * 2048 * 64
                  : Kg + (size_t)((fbase - 2048) >> 6) * 2048 * 64;
  float bv[4], nwv[4];
#pragma unroll
  for (int n = 0; n < 4; ++n) {
    bv[n] = bias[n * 16 + fr];
    nwv[n] = nw[n * 16 + fr] * nscale;
  }
#pragma unroll
  for (int m = 0; m < 2; ++m) {
#pragma unroll
    for (int r = 0; r < 4; ++r) {
      int t = m0 + wr * 32 + m * 16 + hi * 4 + r;
      float v[4];
      float sq = 0.0f;
#pragma unroll
      for (int n = 0; n < 4; ++n) { v[n] = acc[m][n][r] + bv[n]; sq += v[n] * v[n]; }
      sq += __shfl_xor(sq, 1); sq += __shfl_xor(sq, 2);
      sq += __shfl_xor(sq, 4); sq += __shfl_xor(sq, 8);
      float rr = rsqrtf(sq * (1.0f / 64.0f) + 1e-5f);
#pragma unroll
      for (int n = 0; n < 4; ++n) {
        float vn = v[n] * rr * nwv[n];
        float part = __shfl_xor(vn, 1);
        int dh = n * 16 + fr;
        float c = fc[t * 32 + (dh >> 1)];
        float s = fs[t * 32 + (dh >> 1)];
        v[n] = (dh & 1) ? (part * s + vn * c) : (vn * c - part * s);
      }
#pragma unroll
      for (int n = 0; n < 4; ++n)
        outp[(size_t)t * 64 + n * 16 + fr] = f2bf(v[n]);
    }
  }
}

// ---------- bf16 GEMM: C[M][N] (f32,+bias) = A[M][K] * Bt[N][K]^T ----------
// 64x64 tile, BK=64, 2-phase dbuf, chunk-XOR swizzle, n-major XCD order.
__global__ __launch_bounds__(256, 4) void gemm_bt(const u16* __restrict__ A,
                                                  const u16* __restrict__ Bt,
                                                  float* __restrict__ C,
                                                  const float* __restrict__ bias,
                                                  int M, int N, int K) {
  __shared__ alignas(16) u16 As[2][64 * 64];
  __shared__ alignas(16) u16 Bs[2][64 * 64];
  int mt = M >> 6;
  int nwg = gridDim.x;
  int cpx = nwg >> 3;
  int bid = blockIdx.x;
  int swz = (bid & 7) * cpx + (bid >> 3);
  int m0 = (swz % mt) << 6;        // n-major: consecutive swz share the B n-panel
  int n0 = (swz / mt) << 6;
  int tid = threadIdx.x;
  int w = tid >> 6, lane = tid & 63;
  int wr = w >> 1, wc = w & 1;
  int fr = lane & 15, hi = lane >> 4;
  int sw = fr & 7;

  auto STAGE = [&](int buf, int kt) {
#pragma unroll
    for (int i = 0; i < 2; ++i) {
      int chunk = i * 256 + tid;
      int row = chunk >> 3, c = chunk & 7;
      const u16* ga = A + (size_t)(m0 + row) * K + kt + ((c ^ (row & 7)) << 3);
      u16* la = &As[buf][(size_t)(i * 256 + w * 64) * 8];
      __builtin_amdgcn_global_load_lds((const __attribute__((address_space(1))) void*)ga,
                                       (__attribute__((address_space(3))) void*)la, 16, 0, 0);
      const u16* gb = Bt + (size_t)(n0 + row) * K + kt + ((c ^ (row & 7)) << 3);
      u16* lb = &Bs[buf][(size_t)(i * 256 + w * 64) * 8];
      __builtin_amdgcn_global_load_lds((const __attribute__((address_space(1))) void*)gb,
                                       (__attribute__((address_space(3))) void*)lb, 16, 0, 0);
    }
  };

  f32x4 acc[2][2] = {};
  STAGE(0, 0);
  __syncthreads();
  int cur = 0;
  int c0 = (hi ^ sw) << 3, c1 = ((4 + hi) ^ sw) << 3;
  for (int kt = 0; kt < K; kt += 64) {
    if (kt + 64 < K) STAGE(cur ^ 1, kt + 64);
    short8 af[2][2], bf[2][2];
#pragma unroll
    for (int m = 0; m < 2; ++m) {
      int rb = (wr * 32 + m * 16 + fr) * 64;
      af[m][0] = *(const short8*)&As[cur][rb + c0];
      af[m][1] = *(const short8*)&As[cur][rb + c1];
    }
#pragma unroll
    for (int n = 0; n < 2; ++n) {
      int rb = (wc * 32 + n * 16 + fr) * 64;
      bf[n][0] = *(const short8*)&Bs[cur][rb + c0];
      bf[n][1] = *(const short8*)&Bs[cur][rb + c1];
    }
#pragma unroll
    for (int m = 0; m < 2; ++m)
#pragma unroll
      for (int n = 0; n < 2; ++n) {
        acc[m][n] = __builtin_amdgcn_mfma_f32_16x16x32_bf16(af[m][0], bf[n][0], acc[m][n], 0, 0, 0);
        acc[m][n] = __builtin_amdgcn_mfma_f32_16x16x32_bf16(af[m][1], bf[n][1], acc[m][n], 0, 0, 0);
      }
    __syncthreads();
    cur ^= 1;
  }
#pragma unroll
  for (int m = 0; m < 2; ++m) {
#pragma unroll
    for (int n = 0; n < 2; ++n) {
      int gcol = n0 + wc * 32 + n * 16 + fr;
      float bvx = bias ? bias[gcol] : 0.0f;
#pragma unroll
      for (int r = 0; r < 4; ++r) {
        int grow = m0 + wr * 32 + m * 16 + hi * 4 + r;
        C[(size_t)grow * N + gcol] = acc[m][n][r] + bvx;
      }
    }
  }
}

// ---------- causal GQA flash attention (v12: heavy-first remap + lsum-MFMA) ----------
// grid 1024, 64-key tiles, single-sync dbuf LDS, 3 blocks/CU.
__global__ __launch_bounds__(256, 3) void attn_kernel(const u16* __restrict__ Qg,
                                                      const u16* __restrict__ Kg,
                                                      const u16* __restrict__ Vgt,
                                                      const float* __restrict__ qn_w,
                                                      const float* __restrict__ kn_w,
                                                      u16* __restrict__ att) {
  __shared__ alignas(16) u16 Ks[2][64 * 64];         // [key][d], XOR-swizzled rows
  __shared__ alignas(16) u16 Vs[2][64 * 64];         // [d][key], XOR-swizzled rows
  __shared__ alignas(16) uint32_t Ps[4][16 * 36];    // per-wave P: [q=fr][key-pair], stride 36

  // heavy-first balanced remap: grp0 qt=31-q0 (heavy), ..., grp3 qt=q0 (light tail)
  int bid = blockIdx.x;
  int grp = bid >> 8, idx = bid & 255;
  int q0 = idx >> 5, h = idx & 31;
  int qt = (grp == 0) ? 31 - q0 : (grp == 1) ? 16 + q0 : (grp == 2) ? 15 - q0 : q0;
  int kvh = h >> 2;

  int tid = threadIdx.x, w = tid >> 6, lane = tid & 63;
  int fr = lane & 15, hi = lane >> 4, fk = hi * 8;

  float ba = fabsf(qn_w[lane]), bb = fabsf(kn_w[lane]);
#pragma unroll
  for (int off = 32; off >= 1; off >>= 1) {
    ba = fmaxf(ba, __shfl_xor(ba, off));
    bb = fmaxf(bb, __shfl_xor(bb, off));
  }
  float mfix = 11.5416222f * ba * bb;   // uniform softmax max (log2 domain)

  const u16* qbase = Qg + ((size_t)h * 2048 + qt * 64 + w * 16 + fr) * 64;
  short8 qf0 = *(const short8*)(qbase + fk);
  short8 qf1 = *(const short8*)(qbase + 32 + fk);
  short8 ones;
#pragma unroll
  for (int j = 0; j < 8; ++j) ones[j] = (short)0x3F80;   // bf16 1.0
  f32x4 o[4] = {};
  f32x4 o_l = {};   // l-sums via ones-MFMA: o_l[r] = l[q-row hi*4+r]

  // staging: both K and V^T are straight row copies (rows of 64 u16)
  int row0 = tid >> 3, cc = tid & 7;
  const u16* Kbase = Kg + (size_t)kvh * 2048 * 64;
  const u16* Vtbase = Vgt + (size_t)kvh * 64 * 2048;

  short8 k0r, k1r, v0r, v1r;
  auto stage_load = [&](int kt2) {
    const u16* kb = Kbase + (size_t)kt2 * 64 * 64;
    k0r = *(const short8*)(kb + row0 * 64 + cc * 8);
    k1r = *(const short8*)(kb + (32 + row0) * 64 + cc * 8);
    const u16* vb = Vtbase + (size_t)row0 * 2048 + kt2 * 64 + cc * 8;
    v0r = *(const short8*)vb;
    v1r = *(const short8*)(vb + 32 * 2048);
  };
  auto stage_write = [&](int buf) {
    char* KsB = (char*)&Ks[buf][0];
    char* VsB = (char*)&Vs[buf][0];
    int offA = (row0 * 128 + cc * 16) ^ ((row0 & 7) << 4);
    int offB = ((32 + row0) * 128 + cc * 16) ^ ((row0 & 7) << 4);
    *(short8*)(KsB + offA) = k0r;
    *(short8*)(KsB + offB) = k1r;
    *(short8*)(VsB + offA) = v0r;
    *(short8*)(VsB + offB) = v1r;
  };

  stage_load(0);
  stage_write(0);
  __syncthreads();

  uint32_t* Pw = &Ps[w][0];
  int swzr = (fr & 7) << 4;
  int qrow = qt * 64 + w * 16 + fr;

  for (int kt = 0; kt <= qt; ++kt) {
    int buf = kt & 1;
    bool diag = (kt == qt);
    if (!diag) stage_load(kt + 1);   // global loads in flight under this iter's compute
    const char* KsB = (const char*)&Ks[buf][0];
    const char* VsB = (const char*)&Vs[buf][0];
    f32x4 s4[4] = {};
    __builtin_amdgcn_s_setprio(1);
#pragma unroll
    for (int g = 0; g < 4; ++g) {
      int rb = (g * 16 + fr) * 128;
      short8 b0 = *(const short8*)(KsB + ((rb + hi * 16) ^ swzr));
      short8 b1 = *(const short8*)(KsB + ((rb + 64 + hi * 16) ^ swzr));
      s4[g] = __builtin_amdgcn_mfma_f32_16x16x32_bf16(b0, qf0, s4[g], 0, 0, 0);
      s4[g] = __builtin_amdgcn_mfma_f32_16x16x32_bf16(b1, qf1, s4[g], 0, 0, 0);
    }
    __builtin_amdgcn_s_setprio(0);
    if (diag) {
      int kbase = kt * 64 + hi * 4;
#pragma unroll
      for (int g = 0; g < 4; ++g)
#pragma unroll
        for (int r = 0; r < 4; ++r)
          if (kbase + g * 16 + r > qrow) s4[g][r] = -1e30f;
    }
#pragma unroll
    for (int g = 0; g < 4; ++g) {
      float p0 = exp2f(s4[g][0] - mfix);
      float p1 = exp2f(s4[g][1] - mfix);
      float p2 = exp2f(s4[g][2] - mfix);
      float p3 = exp2f(s4[g][3] - mfix);
      uint2 pk = make_uint2(pack_bf16x2(p0, p1), pack_bf16x2(p2, p3));
      *(uint2*)&Pw[fr * 36 + g * 8 + hi * 2] = pk;
    }
    asm volatile("s_waitcnt lgkmcnt(0)" ::: "memory");
    short8 pa0 = *(const short8*)&Pw[fr * 36 + hi * 4];
    short8 pa1 = *(const short8*)&Pw[fr * 36 + 16 + hi * 4];
    __builtin_amdgcn_s_setprio(1);
    o_l = __builtin_amdgcn_mfma_f32_16x16x32_bf16(pa0, ones, o_l, 0, 0, 0);
    o_l = __builtin_amdgcn_mfma_f32_16x16x32_bf16(pa1, ones, o_l, 0, 0, 0);
#pragma unroll
    for (int g2 = 0; g2 < 4; ++g2) {
      int rb = (g2 * 16 + fr) * 128;
      short8 vb0 = *(const short8*)(VsB + ((rb + hi * 16) ^ swzr));
      short8 vb1 = *(const short8*)(VsB + ((rb + 64 + hi * 16) ^ swzr));
      o[g2] = __builtin_amdgcn_mfma_f32_16x16x32_bf16(pa0, vb0, o[g2], 0, 0, 0);
      o[g2] = __builtin_amdgcn_mfma_f32_16x16x32_bf16(pa1, vb1, o[g2], 0, 0, 0);
    }
    __builtin_amdgcn_s_setprio(0);
    if (!diag) stage_write(buf ^ 1);   // write next tile; sync below publishes it
    __syncthreads();                   // ONE barrier per iteration
  }
#pragma unroll
  for (int r = 0; r < 4; ++r) {
    float inv = 1.0f / o_l[r];
    size_t rowoff = (size_t)(qt * 64 + w * 16 + hi * 4 + r) * 2048 + h * 64;
#pragma unroll
    for (int g2 = 0; g2 < 4; ++g2)
      att[rowoff + g2 * 16 + fr] = f2bf(o[g2][r] * inv);
  }
}

extern "C" void kernel_launch(void* const* d_in, const int* in_sizes, int n_in,
                              void* d_out, int out_size, void* d_ws, size_t ws_size,
                              hipStream_t stream) {
  const float* x    = (const float*)d_in[0];
  const float* fc   = (const float*)d_in[1];
  const float* fs   = (const float*)d_in[2];
  // d_in[3] = mask (causal, regenerated in-kernel)
  const float* wq   = (const float*)d_in[4];
  const float* wq_b = (const float*)d_in[5];
  const float* wk   = (const float*)d_in[6];
  const float* wk_b = (const float*)d_in[7];
  const float* wv   = (const float*)d_in[8];
  const float* wv_b = (const float*)d_in[9];
  const float* wo   = (const float*)d_in[10];
  const float* wo_b = (const float*)d_in[11];
  const float* qn   = (const float*)d_in[12];
  const float* kn   = (const float*)d_in[13];
  float* out = (float*)d_out;

  char* ws = (char*)d_ws;
  u16*  xb    = (u16*)(ws);                          //  8 MB  x bf16 [2048][2048]
  u16*  wqkvT = (u16*)(ws + (size_t)(8  << 20));     // 12 MB  [3072][2048] bf16
  u16*  woT   = (u16*)(ws + (size_t)(20 << 20));     //  8 MB  [2048][2048] bf16
  u16*  Qg    = (u16*)(ws + (size_t)(52 << 20));     //  8 MB  [32][2048][64]
  u16*  Kg    = (u16*)(ws + (size_t)(60 << 20));     //  2 MB  [8][2048][64]
  u16*  Vgt   = (u16*)(ws + (size_t)(62 << 20));     //  2 MB  [8][64][2048] (V transposed)
  u16*  att   = (u16*)(ws + (size_t)(64 << 20));     //  8 MB  [2048][2048]

  prep_kernel<<<6656, 256, 0, stream>>>(x, xb, wq, wk, wv, wo, wqkvT, woT);
  gemm_qkv<<<32 * 24, 256, 0, stream>>>(xb, wqkvT, wq_b, wk_b, wv_b, qn, kn, fc, fs, Qg, Kg, Vgt);
  attn_kernel<<<1024, 256, 0, stream>>>(Qg, Kg, Vgt, qn, kn, att);
  gemm_bt<<<32 * 32, 256, 0, stream>>>(att, woT, out, wo_b, 2048, 2048, 2048);
}